// Round 1
// baseline (214.367 us; speedup 1.0000x reference)
//
#include <hip/hip_runtime.h>

typedef __attribute__((ext_vector_type(8))) short short8;
typedef __attribute__((ext_vector_type(4))) float f32x4;
typedef unsigned short u16;

#define MFMA16 __builtin_amdgcn_mfma_f32_16x16x32_bf16

__device__ __forceinline__ u16 f2bf(float f) {
  unsigned int u = __builtin_bit_cast(unsigned int, f);
  u += 0x7fffu + ((u >> 16) & 1u);   // round-to-nearest-even
  return (u16)(u >> 16);
}

// ---------------------------------------------------------------------------
// Setup: convert weights to bf16, build combined bias+mask table
// ws layout: qkvw bf16 [384][128] @0 (98304 B)
//            projw bf16 [128][128] @98304 (32768 B)
//            biasmask f32 [64][4][49][49] @131072 (2458624 B)
// ---------------------------------------------------------------------------
__global__ void setup_misc(const float* __restrict__ qkv_w,
                           const float* __restrict__ proj_w,
                           const float* __restrict__ mask,
                           const float* __restrict__ rpb,
                           const int* __restrict__ rel_idx,
                           u16* __restrict__ qkvw, u16* __restrict__ projw,
                           float* __restrict__ bm) {
  const int i = blockIdx.x * 256 + threadIdx.x;
  if (i < 384 * 128) qkvw[i] = f2bf(qkv_w[i]);
  if (i < 128 * 128) projw[i] = f2bf(proj_w[i]);
  if (i < 64 * 4 * 2401) {
    const int c = i % 2401;            // r*49 + col
    const int h = (i / 2401) & 3;
    const int w = i / (4 * 2401);
    bm[i] = rpb[rel_idx[c] * 4 + h] + mask[w * 2401 + c];
  }
}

// ---------------------------------------------------------------------------
// Fused Swin window-attention block. 1 block = 1 window, 4 waves.
// LDS (per head h): q @ h*10240 [64][40]bf16, k @ h*10240+5120 [64][40]bf16
//                   P @ h*10240 [64][72]bf16 (aliases q||k, own-head only)
// vT @ 40960 + h*4608: [32][72]bf16    tmp @ 40960: [64][136]bf16 (aliases vT)
// total 59392 B
// ---------------------------------------------------------------------------
__global__ __launch_bounds__(256, 2) void swin_fused(
    const float* __restrict__ x, const float* __restrict__ qkv_b,
    const float* __restrict__ proj_b, const u16* __restrict__ qkvw,
    const u16* __restrict__ projw, const float* __restrict__ bm,
    float* __restrict__ out) {
  __shared__ __align__(16) char smem[59392];
  const int b = blockIdx.x;
  const int tid = threadIdx.x;
  const int wv = tid >> 6;
  const int lane = tid & 63;
  const int g = lane >> 4;    // 16-lane group (K-chunk / C-row-group)
  const int ln = lane & 15;   // lane-in-group (M-row for A, N-col for B/C)

  // ---------------- phase 1: qkv = x @ qkv_w^T + b ----------------
  short8 aa[4][4];  // A-frags: x rows, reused across all 24 N-tiles
  const float* xb = x + (size_t)b * (49 * 128);
#pragma unroll
  for (int mt = 0; mt < 4; ++mt) {
    const int row = mt * 16 + ln;
#pragma unroll
    for (int kk = 0; kk < 4; ++kk) {
      short8 v8;
      if (row < 49) {
        const float* p = xb + row * 128 + kk * 32 + g * 8;
        const f32x4 u0 = *(const f32x4*)p;
        const f32x4 u1 = *(const f32x4*)(p + 4);
#pragma unroll
        for (int j = 0; j < 4; ++j) {
          v8[j] = (short)f2bf(u0[j]);
          v8[4 + j] = (short)f2bf(u1[j]);
        }
      } else {
#pragma unroll
        for (int j = 0; j < 8; ++j) v8[j] = 0;
      }
      aa[mt][kk] = v8;
    }
  }
  const float scale = 0.17677669529663687f;  // 1/sqrt(32)
#pragma unroll
  for (int nti = 0; nti < 6; ++nti) {
    const int nt = wv * 6 + nti;
    const int n = nt * 16 + ln;
    const float bias = qkv_b[n];
    short8 bb[4];
#pragma unroll
    for (int kk = 0; kk < 4; ++kk)
      bb[kk] = *(const short8*)(qkvw + n * 128 + kk * 32 + g * 8);
    f32x4 acc[4];
#pragma unroll
    for (int mt = 0; mt < 4; ++mt) acc[mt] = f32x4{bias, bias, bias, bias};
#pragma unroll
    for (int kk = 0; kk < 4; ++kk)
#pragma unroll
      for (int mt = 0; mt < 4; ++mt)
        acc[mt] = MFMA16(aa[mt][kk], bb[kk], acc[mt], 0, 0, 0);
    const int typ = nt >> 3;          // 0=q 1=k 2=v
    const int hh = (nt >> 1) & 3;     // head
    const int hdo = ((nt & 1) << 4) + ln;  // hd index 0..31
#pragma unroll
    for (int mt = 0; mt < 4; ++mt)
#pragma unroll
      for (int i = 0; i < 4; ++i) {
        const int row = mt * 16 + g * 4 + i;
        const float v = acc[mt][i];
        if (typ == 0)
          *(u16*)(smem + hh * 10240 + row * 80 + hdo * 2) = f2bf(v * scale);
        else if (typ == 1)
          *(u16*)(smem + hh * 10240 + 5120 + row * 80 + hdo * 2) = f2bf(v);
        else
          *(u16*)(smem + 40960 + hh * 4608 + hdo * 144 + row * 2) = f2bf(v);
      }
  }
  __syncthreads();

  // ---------------- phase 2: S = q k^T (+bias+mask), softmax -> P ----------
  const int h = wv;
  short8 qa[4], kb[4];
#pragma unroll
  for (int mt = 0; mt < 4; ++mt)
    qa[mt] = *(const short8*)(smem + h * 10240 + (mt * 16 + ln) * 80 + g * 16);
#pragma unroll
  for (int nt = 0; nt < 4; ++nt)
    kb[nt] = *(const short8*)(smem + h * 10240 + 5120 + (nt * 16 + ln) * 80 + g * 16);
  f32x4 s[4][4];
#pragma unroll
  for (int mt = 0; mt < 4; ++mt)
#pragma unroll
    for (int nt = 0; nt < 4; ++nt)
      s[mt][nt] = MFMA16(qa[mt], kb[nt], f32x4{0.f, 0.f, 0.f, 0.f}, 0, 0, 0);
  const float* bmb = bm + ((size_t)((b & 63) * 4 + h)) * 2401;
#pragma unroll
  for (int mt = 0; mt < 4; ++mt)
#pragma unroll
    for (int nt = 0; nt < 4; ++nt)
#pragma unroll
      for (int i = 0; i < 4; ++i) {
        const int r = mt * 16 + g * 4 + i;
        const int c = nt * 16 + ln;
        float v = s[mt][nt][i];
        if (c >= 49)
          v = -1e30f;
        else if (r < 49)
          v += bmb[r * 49 + c];
        s[mt][nt][i] = v;
      }
  const float LOG2E = 1.44269504088896f;
#pragma unroll
  for (int mt = 0; mt < 4; ++mt) {
    float rs[4];
#pragma unroll
    for (int i = 0; i < 4; ++i) {
      float m = s[mt][0][i];
#pragma unroll
      for (int nt = 1; nt < 4; ++nt) m = fmaxf(m, s[mt][nt][i]);
      m = fmaxf(m, __shfl_xor(m, 1));
      m = fmaxf(m, __shfl_xor(m, 2));
      m = fmaxf(m, __shfl_xor(m, 4));
      m = fmaxf(m, __shfl_xor(m, 8));
      float su = 0.f;
#pragma unroll
      for (int nt = 0; nt < 4; ++nt) {
        const float p = exp2f((s[mt][nt][i] - m) * LOG2E);
        s[mt][nt][i] = p;
        su += p;
      }
      su += __shfl_xor(su, 1);
      su += __shfl_xor(su, 2);
      su += __shfl_xor(su, 4);
      su += __shfl_xor(su, 8);
      rs[i] = 1.f / su;
    }
#pragma unroll
    for (int nt = 0; nt < 4; ++nt)
#pragma unroll
      for (int i = 0; i < 4; ++i) {
        const int row = mt * 16 + g * 4 + i;
        const int c = nt * 16 + ln;
        // P aliases own head's q||k; all q/k frag reads already consumed.
        *(u16*)(smem + h * 10240 + row * 144 + c * 2) = f2bf(s[mt][nt][i] * rs[i]);
      }
  }
  __syncthreads();

  // ---------------- phase 3: O_h = P @ v ----------------
  f32x4 o[4][2];
#pragma unroll
  for (int mt = 0; mt < 4; ++mt)
#pragma unroll
    for (int n2 = 0; n2 < 2; ++n2) o[mt][n2] = f32x4{0.f, 0.f, 0.f, 0.f};
#pragma unroll
  for (int kk2 = 0; kk2 < 2; ++kk2) {
    short8 pa[4], vb[2];
#pragma unroll
    for (int mt = 0; mt < 4; ++mt)
      pa[mt] = *(const short8*)(smem + h * 10240 + (mt * 16 + ln) * 144 + kk2 * 64 + g * 16);
#pragma unroll
    for (int n2 = 0; n2 < 2; ++n2)
      vb[n2] = *(const short8*)(smem + 40960 + h * 4608 + (n2 * 16 + ln) * 144 + kk2 * 64 + g * 16);
#pragma unroll
    for (int mt = 0; mt < 4; ++mt)
#pragma unroll
      for (int n2 = 0; n2 < 2; ++n2)
        o[mt][n2] = MFMA16(pa[mt], vb[n2], o[mt][n2], 0, 0, 0);
  }
  __syncthreads();  // all vT reads done block-wide before tmp overlays it
#pragma unroll
  for (int mt = 0; mt < 4; ++mt)
#pragma unroll
    for (int n2 = 0; n2 < 2; ++n2)
#pragma unroll
      for (int i = 0; i < 4; ++i) {
        const int row = mt * 16 + g * 4 + i;
        const int col = h * 32 + n2 * 16 + ln;
        *(u16*)(smem + 40960 + row * 272 + col * 2) = f2bf(o[mt][n2][i]);
      }
  __syncthreads();

  // ---------------- phase 4: out = tmp @ proj_w^T + proj_b ----------------
  short8 at[4][4];
#pragma unroll
  for (int mt = 0; mt < 4; ++mt)
#pragma unroll
    for (int kk = 0; kk < 4; ++kk)
      at[mt][kk] = *(const short8*)(smem + 40960 + (mt * 16 + ln) * 272 + kk * 64 + g * 16);
  float* ob = out + (size_t)b * (49 * 128);
#pragma unroll
  for (int nti = 0; nti < 2; ++nti) {
    const int nt = wv * 2 + nti;
    const int n = nt * 16 + ln;
    const float pb = proj_b[n];
    short8 pw[4];
#pragma unroll
    for (int kk = 0; kk < 4; ++kk)
      pw[kk] = *(const short8*)(projw + n * 128 + kk * 32 + g * 8);
    f32x4 acc[4];
#pragma unroll
    for (int mt = 0; mt < 4; ++mt) acc[mt] = f32x4{pb, pb, pb, pb};
#pragma unroll
    for (int kk = 0; kk < 4; ++kk)
#pragma unroll
      for (int mt = 0; mt < 4; ++mt)
        acc[mt] = MFMA16(at[mt][kk], pw[kk], acc[mt], 0, 0, 0);
#pragma unroll
    for (int mt = 0; mt < 4; ++mt)
#pragma unroll
      for (int i = 0; i < 4; ++i) {
        const int row = mt * 16 + g * 4 + i;
        if (row < 49) ob[row * 128 + n] = acc[mt][i];
      }
  }
}

// ---------------------------------------------------------------------------
extern "C" void kernel_launch(void* const* d_in, const int* in_sizes, int n_in,
                              void* d_out, int out_size, void* d_ws,
                              size_t ws_size, hipStream_t stream) {
  const float* x = (const float*)d_in[0];
  const float* mask = (const float*)d_in[1];
  const float* qkv_w = (const float*)d_in[2];
  const float* qkv_b = (const float*)d_in[3];
  const float* proj_w = (const float*)d_in[4];
  const float* proj_b = (const float*)d_in[5];
  const float* rpb = (const float*)d_in[6];
  const int* rel = (const int*)d_in[7];

  u16* qkvw = (u16*)d_ws;
  u16* projw = (u16*)((char*)d_ws + 98304);
  float* bm = (float*)((char*)d_ws + 131072);  // needs ~2.6 MB total ws

  setup_misc<<<2401, 256, 0, stream>>>(qkv_w, proj_w, mask, rpb, rel, qkvw,
                                       projw, bm);
  swin_fused<<<4096, 256, 0, stream>>>(x, qkv_b, proj_b, qkvw, projw, bm,
                                       (float*)d_out);
}

// Round 4
// 154.256 us; speedup vs baseline: 1.3897x; 1.3897x over previous
//
#include <hip/hip_runtime.h>

typedef __attribute__((ext_vector_type(8))) short short8;
typedef __attribute__((ext_vector_type(4))) float f32x4;
typedef __attribute__((ext_vector_type(2))) unsigned u32x2;
typedef __attribute__((ext_vector_type(4))) unsigned u32x4;
typedef unsigned short u16;

#define MFMA16 __builtin_amdgcn_mfma_f32_16x16x32_bf16

__device__ __forceinline__ u16 f2bf(float f) {
  unsigned u = __builtin_bit_cast(unsigned, f);
  u += 0x7fffu + ((u >> 16) & 1u);  // RTNE
  return (u16)(u >> 16);
}
__device__ __forceinline__ unsigned cvtpk(float a, float b) {
  return (unsigned)f2bf(a) | ((unsigned)f2bf(b) << 16);
}
__device__ __forceinline__ float bitf(unsigned u) {
  return __builtin_bit_cast(float, u);
}

// ---------------------------------------------------------------------------
// Setup: bf16 weights (q pre-scaled), scaled bias, bias+mask table
// bmsw[w][h][tq(64)][tk(64)] bf16.
// ws: qkvw@0 (98304B) projw@98304 (32768B) qkvbs@131072 (1536B)
//     bmsw@133120 (2097152B)
// ---------------------------------------------------------------------------
__global__ void setup_misc(const float* __restrict__ qkv_w,
                           const float* __restrict__ qkv_b,
                           const float* __restrict__ proj_w,
                           const float* __restrict__ mask,
                           const float* __restrict__ rpb,
                           const int* __restrict__ rel_idx,
                           u16* __restrict__ qkvw, u16* __restrict__ projw,
                           float* __restrict__ qkvbs, u16* __restrict__ bmsw) {
  const int i = blockIdx.x * 256 + threadIdx.x;
  const float scale = 0.17677669529663687f;  // 1/sqrt(32)
  if (i < 384 * 128) qkvw[i] = f2bf(qkv_w[i] * (i < 16384 ? scale : 1.f));
  if (i < 128 * 128) projw[i] = f2bf(proj_w[i]);
  if (i < 384) qkvbs[i] = qkv_b[i] * (i < 128 ? scale : 1.f);
  {  // i in [0,1048576): w=i>>14 h=(i>>12)&3 tq=(i>>6)&63 tk=i&63
    const int w = i >> 14, h = (i >> 12) & 3, tq = (i >> 6) & 63, tk = i & 63;
    float v = 0.f;
    if (tq < 49 && tk < 49)
      v = rpb[rel_idx[tq * 49 + tk] * 4 + h] + mask[w * 2401 + tq * 49 + tk];
    bmsw[i] = f2bf(v);
  }
}

// ---------------------------------------------------------------------------
// Fused Swin block. 1 block = 1 window, wave h owns head h. No transposes:
// every MFMA oriented so C-quads store contiguously into the next layout.
// LDS (49152 B), all rows XOR-swizzled:
//  qT[h] @ h*8192        : [64 tok][64B: 32 d]   key=(row&3)<<4
//  kT[h] @ h*8192+4096   : [64 tok][64B: 32 d]   key=(row&3)<<4
//  P[h]  @ h*8192        : [64 tq][128B: 64 tk]  key=(row&7)<<4 (alias qT||kT)
//  VT[h] @ 32768+h*4096  : [32 d][128B: 64 tk]   key=(row&7)<<4
//  tmp   @ 32768         : [64 tok][256B: 128ch] key=(row&7)<<4 (alias all VT)
// ---------------------------------------------------------------------------
__global__ __launch_bounds__(256, 3) void swin_fused(
    const float* __restrict__ x, const float* __restrict__ qkvbs,
    const float* __restrict__ proj_b, const u16* __restrict__ qkvw,
    const u16* __restrict__ projw, const u16* __restrict__ bmsw,
    float* __restrict__ out) {
  __shared__ __align__(16) char smem[49152];
  const int b = blockIdx.x;
  const int tid = threadIdx.x;
  const int h = tid >> 6;  // wave = head
  const int lane = tid & 63;
  const int g = lane >> 4;
  const int ln = lane & 15;
  const unsigned key3 = (unsigned)((ln & 3) << 4);
  const unsigned key7 = (unsigned)((ln & 7) << 4);

  // ---------------- phase 1: x frags (A for v, B for q/k) ----------------
  short8 aa[4][4];
  const float* xb = x + (size_t)b * (49 * 128);
#pragma unroll
  for (int mt = 0; mt < 4; ++mt) {
    const int row = mt * 16 + ln;
#pragma unroll
    for (int kk = 0; kk < 4; ++kk) {
      if (row < 49) {
        const float* p = xb + row * 128 + kk * 32 + g * 8;
        const f32x4 u0 = *(const f32x4*)p;
        const f32x4 u1 = *(const f32x4*)(p + 4);
        u32x4 r = {cvtpk(u0[0], u0[1]), cvtpk(u0[2], u0[3]),
                   cvtpk(u1[0], u1[1]), cvtpk(u1[2], u1[3])};
        aa[mt][kk] = __builtin_bit_cast(short8, r);
      } else {
        u32x4 r = {0u, 0u, 0u, 0u};
        aa[mt][kk] = __builtin_bit_cast(short8, r);
      }
    }
  }
  // q^T, k^T: C[ch][tok] = mfma(W, x)
#pragma unroll
  for (int qk = 0; qk < 2; ++qk)
#pragma unroll
    for (int Mt = 0; Mt < 2; ++Mt) {
      const int n = qk * 128 + h * 32 + Mt * 16 + ln;
      short8 wf[4];
#pragma unroll
      for (int kk = 0; kk < 4; ++kk)
        wf[kk] = *(const short8*)(qkvw + n * 128 + kk * 32 + g * 8);
      const f32x4 bq = *(const f32x4*)(qkvbs + qk * 128 + h * 32 + Mt * 16 + g * 4);
      f32x4 acc[4];
#pragma unroll
      for (int Nt = 0; Nt < 4; ++Nt) acc[Nt] = bq;
#pragma unroll
      for (int kk = 0; kk < 4; ++kk)
#pragma unroll
        for (int Nt = 0; Nt < 4; ++Nt)
          acc[Nt] = MFMA16(wf[kk], aa[Nt][kk], acc[Nt], 0, 0, 0);
#pragma unroll
      for (int Nt = 0; Nt < 4; ++Nt) {
        const int tok = Nt * 16 + ln;
        const u32x2 d2 = {cvtpk(acc[Nt][0], acc[Nt][1]),
                          cvtpk(acc[Nt][2], acc[Nt][3])};
        *(u32x2*)(smem + h * 8192 + qk * 4096 + tok * 64 +
                  (((unsigned)(Mt * 32 + g * 8)) ^ key3)) = d2;
      }
    }
  // v: C[tok][d] = mfma(x, W) -> store VT[d][tok]
#pragma unroll
  for (int dt = 0; dt < 2; ++dt) {
    const int n = 256 + h * 32 + dt * 16 + ln;
    short8 wf[4];
#pragma unroll
    for (int kk = 0; kk < 4; ++kk)
      wf[kk] = *(const short8*)(qkvw + n * 128 + kk * 32 + g * 8);
    const float bv = qkvbs[n];
    f32x4 acc[4];
#pragma unroll
    for (int mt = 0; mt < 4; ++mt) acc[mt] = f32x4{bv, bv, bv, bv};
#pragma unroll
    for (int kk = 0; kk < 4; ++kk)
#pragma unroll
      for (int mt = 0; mt < 4; ++mt)
        acc[mt] = MFMA16(aa[mt][kk], wf[kk], acc[mt], 0, 0, 0);
    const int d = dt * 16 + ln;
#pragma unroll
    for (int mt = 0; mt < 4; ++mt) {
      const u32x2 d2 = {cvtpk(acc[mt][0], acc[mt][1]),
                        cvtpk(acc[mt][2], acc[mt][3])};
      *(u32x2*)(smem + 32768 + h * 4096 + d * 128 +
                (((unsigned)(mt * 32 + g * 8)) ^ key7)) = d2;
    }
  }
  // no barrier: q/k/v/P traffic is wave-local until the tmp overlay

  // ---------------- phase 2: S^T = mfma(k, q), softmax over tk ----------
  short8 kf[4], qf[4];
#pragma unroll
  for (int t = 0; t < 4; ++t) {
    const unsigned colb = ((unsigned)(g * 16)) ^ key3;
    kf[t] = *(const short8*)(smem + h * 8192 + 4096 + (t * 16 + ln) * 64 + colb);
    qf[t] = *(const short8*)(smem + h * 8192 + (t * 16 + ln) * 64 + colb);
  }
  f32x4 s[4][4];  // [tkt][tqt]
#pragma unroll
  for (int tkt = 0; tkt < 4; ++tkt)
#pragma unroll
    for (int tqt = 0; tqt < 4; ++tqt)
      s[tkt][tqt] = MFMA16(kf[tkt], qf[tqt], f32x4{0.f, 0.f, 0.f, 0.f}, 0, 0, 0);
  const char* bmb = (const char*)(bmsw + ((size_t)((b & 63) * 4 + h)) * 4096);
#pragma unroll
  for (int tqt = 0; tqt < 4; ++tqt) {
    const int tq = tqt * 16 + ln;
#pragma unroll
    for (int tkt = 0; tkt < 4; ++tkt) {
      const u32x2 pk = *(const u32x2*)(bmb + tq * 128 + tkt * 32 + g * 8);
      s[tkt][tqt][0] += bitf(pk[0] << 16);
      s[tkt][tqt][1] += bitf(pk[0] & 0xffff0000u);
      s[tkt][tqt][2] += bitf(pk[1] << 16);
      s[tkt][tqt][3] += bitf(pk[1] & 0xffff0000u);
    }
  }
  // mask tk >= 49 (tkt==3, g*4+i>0)
#pragma unroll
  for (int tqt = 0; tqt < 4; ++tqt)
#pragma unroll
    for (int i = 0; i < 4; ++i)
      if (g * 4 + i > 0) s[3][tqt][i] = -1e30f;
  const float LOG2E = 1.44269504088896f;
#pragma unroll
  for (int tqt = 0; tqt < 4; ++tqt) {
    float m = s[0][tqt][0];
#pragma unroll
    for (int tkt = 0; tkt < 4; ++tkt)
#pragma unroll
      for (int i = 0; i < 4; ++i) m = fmaxf(m, s[tkt][tqt][i]);
    m = fmaxf(m, __shfl_xor(m, 16));
    m = fmaxf(m, __shfl_xor(m, 32));
    float su = 0.f;
#pragma unroll
    for (int tkt = 0; tkt < 4; ++tkt)
#pragma unroll
      for (int i = 0; i < 4; ++i) {
        const float p = exp2f((s[tkt][tqt][i] - m) * LOG2E);
        s[tkt][tqt][i] = p;
        su += p;
      }
    su += __shfl_xor(su, 16);
    su += __shfl_xor(su, 32);
    const float r = 1.f / su;
    const int tq = tqt * 16 + ln;
#pragma unroll
    for (int tkt = 0; tkt < 4; ++tkt) {
      const u32x2 d2 = {cvtpk(s[tkt][tqt][0] * r, s[tkt][tqt][1] * r),
                        cvtpk(s[tkt][tqt][2] * r, s[tkt][tqt][3] * r)};
      *(u32x2*)(smem + h * 8192 + tq * 128 +
                (((unsigned)(tkt * 32 + g * 8)) ^ key7)) = d2;
    }
  }

  // ---------------- phase 3: O^T = mfma(v, P) ----------------
  short8 vf[2][2], pf[4][2];
#pragma unroll
  for (int Mt = 0; Mt < 2; ++Mt)
#pragma unroll
    for (int kk2 = 0; kk2 < 2; ++kk2)
      vf[Mt][kk2] = *(const short8*)(smem + 32768 + h * 4096 +
                                     (Mt * 16 + ln) * 128 +
                                     (((unsigned)(kk2 * 64 + g * 16)) ^ key7));
#pragma unroll
  for (int Nt = 0; Nt < 4; ++Nt)
#pragma unroll
    for (int kk2 = 0; kk2 < 2; ++kk2)
      pf[Nt][kk2] = *(const short8*)(smem + h * 8192 + (Nt * 16 + ln) * 128 +
                                     (((unsigned)(kk2 * 64 + g * 16)) ^ key7));
  f32x4 o[2][4];
#pragma unroll
  for (int Mt = 0; Mt < 2; ++Mt)
#pragma unroll
    for (int Nt = 0; Nt < 4; ++Nt) o[Mt][Nt] = f32x4{0.f, 0.f, 0.f, 0.f};
#pragma unroll
  for (int kk2 = 0; kk2 < 2; ++kk2)
#pragma unroll
    for (int Mt = 0; Mt < 2; ++Mt)
#pragma unroll
      for (int Nt = 0; Nt < 4; ++Nt)
        o[Mt][Nt] = MFMA16(vf[Mt][kk2], pf[Nt][kk2], o[Mt][Nt], 0, 0, 0);
  __syncthreads();  // all VT reads complete before tmp overlays it
#pragma unroll
  for (int Mt = 0; Mt < 2; ++Mt)
#pragma unroll
    for (int Nt = 0; Nt < 4; ++Nt) {
      const int tok = Nt * 16 + ln;
      const u32x2 d2 = {cvtpk(o[Mt][Nt][0], o[Mt][Nt][1]),
                        cvtpk(o[Mt][Nt][2], o[Mt][Nt][3])};
      *(u32x2*)(smem + 32768 + tok * 256 +
                (((unsigned)((h * 32 + Mt * 16 + g * 4) * 2)) ^ key7)) = d2;
    }
  __syncthreads();

  // ---------------- phase 4: out = mfma(tmp, projW) + proj_b ----------------
  short8 at[4][4];
#pragma unroll
  for (int mt = 0; mt < 4; ++mt)
#pragma unroll
    for (int kk = 0; kk < 4; ++kk)
      at[mt][kk] = *(const short8*)(smem + 32768 + (mt * 16 + ln) * 256 +
                                    (((unsigned)(kk * 64 + g * 16)) ^ key7));
  float* ob = out + (size_t)b * (49 * 128);
#pragma unroll
  for (int nti = 0; nti < 2; ++nti) {
    const int n = (h * 2 + nti) * 16 + ln;
    const float pb = proj_b[n];
    short8 pw[4];
#pragma unroll
    for (int kk = 0; kk < 4; ++kk)
      pw[kk] = *(const short8*)(projw + n * 128 + kk * 32 + g * 8);
    f32x4 acc[4];
#pragma unroll
    for (int mt = 0; mt < 4; ++mt) acc[mt] = f32x4{pb, pb, pb, pb};
#pragma unroll
    for (int kk = 0; kk < 4; ++kk)
#pragma unroll
      for (int mt = 0; mt < 4; ++mt)
        acc[mt] = MFMA16(at[mt][kk], pw[kk], acc[mt], 0, 0, 0);
#pragma unroll
    for (int mt = 0; mt < 4; ++mt)
#pragma unroll
      for (int i = 0; i < 4; ++i) {
        const int row = mt * 16 + g * 4 + i;
        if (row < 49) ob[row * 128 + n] = acc[mt][i];
      }
  }
}

// ---------------------------------------------------------------------------
extern "C" void kernel_launch(void* const* d_in, const int* in_sizes, int n_in,
                              void* d_out, int out_size, void* d_ws,
                              size_t ws_size, hipStream_t stream) {
  const float* x = (const float*)d_in[0];
  const float* mask = (const float*)d_in[1];
  const float* qkv_w = (const float*)d_in[2];
  const float* qkv_b = (const float*)d_in[3];
  const float* proj_w = (const float*)d_in[4];
  const float* proj_b = (const float*)d_in[5];
  const float* rpb = (const float*)d_in[6];
  const int* rel = (const int*)d_in[7];

  u16* qkvw = (u16*)d_ws;
  u16* projw = (u16*)((char*)d_ws + 98304);
  float* qkvbs = (float*)((char*)d_ws + 131072);
  u16* bmsw = (u16*)((char*)d_ws + 133120);  // 2 MB; total ws use ~2.2 MB

  setup_misc<<<4096, 256, 0, stream>>>(qkv_w, qkv_b, proj_w, mask, rpb, rel,
                                       qkvw, projw, qkvbs, bmsw);
  swin_fused<<<4096, 256, 0, stream>>>(x, qkvbs, proj_b, qkvw, projw, bmsw,
                                       (float*)d_out);
}

// Round 8
// 153.125 us; speedup vs baseline: 1.3999x; 1.0074x over previous
//
#include <hip/hip_runtime.h>

typedef __attribute__((ext_vector_type(8))) short short8;
typedef __attribute__((ext_vector_type(4))) float f32x4;
typedef __attribute__((ext_vector_type(2))) unsigned u32x2;
typedef __attribute__((ext_vector_type(4))) unsigned u32x4;
typedef unsigned short u16;

#define MFMA16 __builtin_amdgcn_mfma_f32_16x16x32_bf16

__device__ __forceinline__ u16 f2bf(float f) {
  unsigned u = __builtin_bit_cast(unsigned, f);
  u += 0x7fffu + ((u >> 16) & 1u);  // RTNE
  return (u16)(u >> 16);
}
// R4-proven manual pack (the v_cvt_pk_bf16_f32 asm variant NaN'd in R5/R6)
__device__ __forceinline__ unsigned cvtpk(float a, float b) {
  return (unsigned)f2bf(a) | ((unsigned)f2bf(b) << 16);
}
__device__ __forceinline__ float bitf(unsigned u) {
  return __builtin_bit_cast(float, u);
}

// ---------------------------------------------------------------------------
// Setup: bf16 weights (q pre-scaled by scale*log2e), scaled bias, bias+mask
// table bmsw[w][h][tq(64)][tk(64)] bf16, pre-multiplied by log2e.
// Sentinel -30000 ONLY for tk>=49 (reduction axis): with max-subtraction,
// exp2(-29952 - m) == 0 -> free mask. Padded tq columns keep bias 0; their
// softmax is finite garbage discarded by the row<49 output guard.
// ws: qkvw@0 (98304B) projw@98304 (32768B) qkvbs@131072 (1536B)
//     bmsw@133120 (2097152B)
// ---------------------------------------------------------------------------
__global__ void setup_misc(const float* __restrict__ qkv_w,
                           const float* __restrict__ qkv_b,
                           const float* __restrict__ proj_w,
                           const float* __restrict__ mask,
                           const float* __restrict__ rpb,
                           const int* __restrict__ rel_idx,
                           u16* __restrict__ qkvw, u16* __restrict__ projw,
                           float* __restrict__ qkvbs, u16* __restrict__ bmsw) {
  const int i = blockIdx.x * 256 + threadIdx.x;
  const float LOG2E = 1.44269504088896f;
  const float qsc = 0.17677669529663687f * LOG2E;  // 1/sqrt(32) * log2e
  if (i < 384 * 128) qkvw[i] = f2bf(qkv_w[i] * (i < 16384 ? qsc : 1.f));
  if (i < 128 * 128) projw[i] = f2bf(proj_w[i]);
  if (i < 384) qkvbs[i] = qkv_b[i] * (i < 128 ? qsc : 1.f);
  {  // i in [0,1048576): w=i>>14 h=(i>>12)&3 tq=(i>>6)&63 tk=i&63
    const int w = i >> 14, h = (i >> 12) & 3, tq = (i >> 6) & 63, tk = i & 63;
    float v = 0.f;
    if (tk >= 49)
      v = -30000.f;  // mask the reduction axis only
    else if (tq < 49)
      v = (rpb[rel_idx[tq * 49 + tk] * 4 + h] + mask[w * 2401 + tq * 49 + tk]) *
          LOG2E;
    bmsw[i] = f2bf(v);
  }
}

// ---------------------------------------------------------------------------
// Fused Swin block. 1 block = 1 window, wave h owns head h. No transposes:
// every MFMA oriented so C-quads store contiguously into the next layout.
// LDS (49152 B), all rows XOR-swizzled (key is row-determined on both sides):
//  qT[h] @ h*8192        : [64 tok][64B: 32 d]   key=(row&3)<<4
//  kT[h] @ h*8192+4096   : [64 tok][64B: 32 d]   key=(row&3)<<4
//  P[h]  @ h*8192        : [64 tq][128B: 64 tk]  key=(row&7)<<4 (alias qT||kT)
//  VT[h] @ 32768+h*4096  : [32 d][128B: 64 tk]   key=(row&7)<<4
//  tmp   @ 32768         : [64 tok][256B: 128ch] key=(row&7)<<4 (alias all VT)
// ---------------------------------------------------------------------------
__global__ __launch_bounds__(256, 3) void swin_fused(
    const float* __restrict__ x, const float* __restrict__ qkvbs,
    const float* __restrict__ proj_b, const u16* __restrict__ qkvw,
    const u16* __restrict__ projw, const u16* __restrict__ bmsw,
    float* __restrict__ out) {
  __shared__ __align__(16) char smem[49152];
  const int b = blockIdx.x;
  const int tid = threadIdx.x;
  const int h = tid >> 6;  // wave = head
  const int lane = tid & 63;
  const int g = lane >> 4;
  const int ln = lane & 15;
  const unsigned key3 = (unsigned)((ln & 3) << 4);
  const unsigned key7 = (unsigned)((ln & 7) << 4);

  // ---------------- phase 1: x frags (A for v, B for q/k) ----------------
  short8 aa[4][4];
  const float* xb = x + (size_t)b * (49 * 128);
#pragma unroll
  for (int mt = 0; mt < 4; ++mt) {
    const int row = mt * 16 + ln;
#pragma unroll
    for (int kk = 0; kk < 4; ++kk) {
      if (row < 49) {
        const float* p = xb + row * 128 + kk * 32 + g * 8;
        const f32x4 u0 = *(const f32x4*)p;
        const f32x4 u1 = *(const f32x4*)(p + 4);
        u32x4 r = {cvtpk(u0[0], u0[1]), cvtpk(u0[2], u0[3]),
                   cvtpk(u1[0], u1[1]), cvtpk(u1[2], u1[3])};
        aa[mt][kk] = __builtin_bit_cast(short8, r);
      } else {
        u32x4 r = {0u, 0u, 0u, 0u};
        aa[mt][kk] = __builtin_bit_cast(short8, r);
      }
    }
  }
  // q^T, k^T: C[ch][tok] = mfma(W, x)
#pragma unroll
  for (int qk = 0; qk < 2; ++qk)
#pragma unroll
    for (int Mt = 0; Mt < 2; ++Mt) {
      const int n = qk * 128 + h * 32 + Mt * 16 + ln;
      short8 wf[4];
#pragma unroll
      for (int kk = 0; kk < 4; ++kk)
        wf[kk] = *(const short8*)(qkvw + n * 128 + kk * 32 + g * 8);
      const f32x4 bq = *(const f32x4*)(qkvbs + qk * 128 + h * 32 + Mt * 16 + g * 4);
      f32x4 acc[4];
#pragma unroll
      for (int Nt = 0; Nt < 4; ++Nt) acc[Nt] = bq;
#pragma unroll
      for (int kk = 0; kk < 4; ++kk)
#pragma unroll
        for (int Nt = 0; Nt < 4; ++Nt)
          acc[Nt] = MFMA16(wf[kk], aa[Nt][kk], acc[Nt], 0, 0, 0);
#pragma unroll
      for (int Nt = 0; Nt < 4; ++Nt) {
        const int tok = Nt * 16 + ln;
        const u32x2 d2 = {cvtpk(acc[Nt][0], acc[Nt][1]),
                          cvtpk(acc[Nt][2], acc[Nt][3])};
        *(u32x2*)(smem + h * 8192 + qk * 4096 + tok * 64 +
                  (((unsigned)(Mt * 32 + g * 8)) ^ key3)) = d2;
      }
    }
  // v: C[tok][d] = mfma(x, W) -> store VT[d][tok]
#pragma unroll
  for (int dt = 0; dt < 2; ++dt) {
    const int n = 256 + h * 32 + dt * 16 + ln;
    short8 wf[4];
#pragma unroll
    for (int kk = 0; kk < 4; ++kk)
      wf[kk] = *(const short8*)(qkvw + n * 128 + kk * 32 + g * 8);
    const float bv = qkvbs[n];
    f32x4 acc[4];
#pragma unroll
    for (int mt = 0; mt < 4; ++mt) acc[mt] = f32x4{bv, bv, bv, bv};
#pragma unroll
    for (int kk = 0; kk < 4; ++kk)
#pragma unroll
      for (int mt = 0; mt < 4; ++mt)
        acc[mt] = MFMA16(aa[mt][kk], wf[kk], acc[mt], 0, 0, 0);
    const int d = dt * 16 + ln;
#pragma unroll
    for (int mt = 0; mt < 4; ++mt) {
      const u32x2 d2 = {cvtpk(acc[mt][0], acc[mt][1]),
                        cvtpk(acc[mt][2], acc[mt][3])};
      *(u32x2*)(smem + 32768 + h * 4096 + d * 128 +
                (((unsigned)(mt * 32 + g * 8)) ^ key7)) = d2;
    }
  }
  // no barrier: q/k/v/P traffic is wave-local until the tmp overlay

  // ---------------- phase 2: S^T = mfma(k, q) + bias-as-C-init ----------
  // bias loads first (L2) so latency overlaps the LDS frag reads
  const char* bmb = (const char*)(bmsw + ((size_t)((b & 63) * 4 + h)) * 4096);
  u32x2 bmr[4][4];
#pragma unroll
  for (int tkt = 0; tkt < 4; ++tkt)
#pragma unroll
    for (int tqt = 0; tqt < 4; ++tqt)
      bmr[tkt][tqt] =
          *(const u32x2*)(bmb + (tqt * 16 + ln) * 128 + tkt * 32 + g * 8);
  short8 kf[4], qf[4];
#pragma unroll
  for (int t = 0; t < 4; ++t) {
    const unsigned colb = ((unsigned)(g * 16)) ^ key3;
    kf[t] = *(const short8*)(smem + h * 8192 + 4096 + (t * 16 + ln) * 64 + colb);
    qf[t] = *(const short8*)(smem + h * 8192 + (t * 16 + ln) * 64 + colb);
  }
  f32x4 s[4][4];  // [tkt][tqt]; exponents base-2 (log2e folded into q & bias)
#pragma unroll
  for (int tkt = 0; tkt < 4; ++tkt)
#pragma unroll
    for (int tqt = 0; tqt < 4; ++tqt) {
      const f32x4 cin = {bitf(bmr[tkt][tqt][0] << 16),
                         bitf(bmr[tkt][tqt][0] & 0xffff0000u),
                         bitf(bmr[tkt][tqt][1] << 16),
                         bitf(bmr[tkt][tqt][1] & 0xffff0000u)};
      s[tkt][tqt] = MFMA16(kf[tkt], qf[tqt], cin, 0, 0, 0);
    }
  // max-subtraction (base-2 units): guarantees exp2 <= 1, su in [1,64] ->
  // the whole downstream pipeline is provably inf/NaN-free.
#pragma unroll
  for (int tqt = 0; tqt < 4; ++tqt) {
    const int tq = tqt * 16 + ln;
    float m = s[0][tqt][0];
#pragma unroll
    for (int tkt = 0; tkt < 4; ++tkt)
#pragma unroll
      for (int i = 0; i < 4; ++i) m = fmaxf(m, s[tkt][tqt][i]);
    m = fmaxf(m, __shfl_xor(m, 16));
    m = fmaxf(m, __shfl_xor(m, 32));
    float su = 0.f;
#pragma unroll
    for (int tkt = 0; tkt < 4; ++tkt)
#pragma unroll
      for (int i = 0; i < 4; ++i) {
        const float p = __builtin_amdgcn_exp2f(s[tkt][tqt][i] - m);
        s[tkt][tqt][i] = p;
        su += p;
      }
    su += __shfl_xor(su, 16);
    su += __shfl_xor(su, 32);
    const float rs = __builtin_amdgcn_rcpf(su);  // su >= 1 -> safe
#pragma unroll
    for (int tkt = 0; tkt < 4; ++tkt) {
      const u32x2 d2 = {cvtpk(s[tkt][tqt][0] * rs, s[tkt][tqt][1] * rs),
                        cvtpk(s[tkt][tqt][2] * rs, s[tkt][tqt][3] * rs)};
      *(u32x2*)(smem + h * 8192 + tq * 128 +
                (((unsigned)(tkt * 32 + g * 8)) ^ key7)) = d2;  // P (normed)
    }
  }

  // ---------------- phase 3: O^T = mfma(v, P) ----------------
  short8 vf[2][2], pf[4][2];
#pragma unroll
  for (int Mt = 0; Mt < 2; ++Mt)
#pragma unroll
    for (int kk2 = 0; kk2 < 2; ++kk2)
      vf[Mt][kk2] = *(const short8*)(smem + 32768 + h * 4096 +
                                     (Mt * 16 + ln) * 128 +
                                     (((unsigned)(kk2 * 64 + g * 16)) ^ key7));
#pragma unroll
  for (int Nt = 0; Nt < 4; ++Nt)
#pragma unroll
    for (int kk2 = 0; kk2 < 2; ++kk2)
      pf[Nt][kk2] = *(const short8*)(smem + h * 8192 + (Nt * 16 + ln) * 128 +
                                     (((unsigned)(kk2 * 64 + g * 16)) ^ key7));
  f32x4 o[2][4];
#pragma unroll
  for (int Mt = 0; Mt < 2; ++Mt)
#pragma unroll
    for (int Nt = 0; Nt < 4; ++Nt) o[Mt][Nt] = f32x4{0.f, 0.f, 0.f, 0.f};
#pragma unroll
  for (int kk2 = 0; kk2 < 2; ++kk2)
#pragma unroll
    for (int Mt = 0; Mt < 2; ++Mt)
#pragma unroll
      for (int Nt = 0; Nt < 4; ++Nt)
        o[Mt][Nt] = MFMA16(vf[Mt][kk2], pf[Nt][kk2], o[Mt][Nt], 0, 0, 0);
  __syncthreads();  // all VT reads complete before tmp overlays it
#pragma unroll
  for (int Mt = 0; Mt < 2; ++Mt)
#pragma unroll
    for (int Nt = 0; Nt < 4; ++Nt) {
      const int tok = Nt * 16 + ln;
      const u32x2 d2 = {cvtpk(o[Mt][Nt][0], o[Mt][Nt][1]),
                        cvtpk(o[Mt][Nt][2], o[Mt][Nt][3])};
      *(u32x2*)(smem + 32768 + tok * 256 +
                (((unsigned)((h * 32 + Mt * 16 + g * 4) * 2)) ^ key7)) = d2;
    }
  __syncthreads();

  // ---------------- phase 4: out = mfma(tmp, projW) + proj_b ----------------
  short8 at[4][4];
#pragma unroll
  for (int mt = 0; mt < 4; ++mt)
#pragma unroll
    for (int kk = 0; kk < 4; ++kk)
      at[mt][kk] = *(const short8*)(smem + 32768 + (mt * 16 + ln) * 256 +
                                    (((unsigned)(kk * 64 + g * 16)) ^ key7));
  float* ob = out + (size_t)b * (49 * 128);
#pragma unroll
  for (int nti = 0; nti < 2; ++nti) {
    const int n = (h * 2 + nti) * 16 + ln;
    const float pb = proj_b[n];
    short8 pw[4];
#pragma unroll
    for (int kk = 0; kk < 4; ++kk)
      pw[kk] = *(const short8*)(projw + n * 128 + kk * 32 + g * 8);
    f32x4 acc[4];
#pragma unroll
    for (int mt = 0; mt < 4; ++mt) acc[mt] = f32x4{pb, pb, pb, pb};
#pragma unroll
    for (int kk = 0; kk < 4; ++kk)
#pragma unroll
      for (int mt = 0; mt < 4; ++mt)
        acc[mt] = MFMA16(at[mt][kk], pw[kk], acc[mt], 0, 0, 0);
#pragma unroll
    for (int mt = 0; mt < 4; ++mt)
#pragma unroll
      for (int i = 0; i < 4; ++i) {
        const int row = mt * 16 + g * 4 + i;
        if (row < 49) ob[row * 128 + n] = acc[mt][i];
      }
  }
}

// ---------------------------------------------------------------------------
extern "C" void kernel_launch(void* const* d_in, const int* in_sizes, int n_in,
                              void* d_out, int out_size, void* d_ws,
                              size_t ws_size, hipStream_t stream) {
  const float* x = (const float*)d_in[0];
  const float* mask = (const float*)d_in[1];
  const float* qkv_w = (const float*)d_in[2];
  const float* qkv_b = (const float*)d_in[3];
  const float* proj_w = (const float*)d_in[4];
  const float* proj_b = (const float*)d_in[5];
  const float* rpb = (const float*)d_in[6];
  const int* rel = (const int*)d_in[7];

  u16* qkvw = (u16*)d_ws;
  u16* projw = (u16*)((char*)d_ws + 98304);
  float* qkvbs = (float*)((char*)d_ws + 131072);
  u16* bmsw = (u16*)((char*)d_ws + 133120);  // 2 MB; total ws use ~2.2 MB

  setup_misc<<<4096, 256, 0, stream>>>(qkv_w, qkv_b, proj_w, mask, rpb, rel,
                                       qkvw, projw, qkvbs, bmsw);
  swin_fused<<<4096, 256, 0, stream>>>(x, qkvbs, proj_b, qkvw, projw, bmsw,
                                       (float*)d_out);
}